// Round 7
// baseline (539.813 us; speedup 1.0000x reference)
//
#include <hip/hip_runtime.h>
#include <math.h>

#define N_NODES  100000
#define N_FEAT   128
#define N_HID    64
#define N_CLASS  10
#define N_GRAPHS 1000
#define N_EDGES  1600000
#define SCAN_NB  98        // ceil(100000/1024)
#define NPASS    6
#define PRANGE   16667     // ceil(100000/6)
#define NTILES   1563      // ceil(100000/64)
#define HIST_NB  2048

// ---- fused: blocks [0,HIST_NB) = degree histogram (rank = atomic return);
// ---- blocks [HIST_NB, HIST_NB+NTILES) = pre GEMM h0 = x@pre_w + pre_b.
// Independent work overlapped in one dispatch: pre's VALU work hides behind
// hist's atomic latency (hist: VALUBusy 0.45% standalone).
__global__ __launch_bounds__(256, 4) void pre_hist_kernel(
    const float* __restrict__ x, const float* __restrict__ W,
    const float* __restrict__ b, float* __restrict__ h,
    const int* __restrict__ ei, int* __restrict__ deg, int* __restrict__ rank)
{
    __shared__ float xs[64][68];    // x half-tile [m][kk]
    __shared__ float ws[64][68];    // W half     [kk][c]
    const int tid = threadIdx.x;

    if (blockIdx.x < HIST_NB) {
        const int stride = HIST_NB * 256;
        for (int e = blockIdx.x * 256 + tid; e < N_EDGES; e += stride)
            rank[e] = atomicAdd(&deg[ei[N_EDGES + e]], 1);
        return;
    }

    const int tx = tid & 15, ty = tid >> 4;
    const int n0 = (blockIdx.x - HIST_NB) * 64;

    float acc[4][4];
#pragma unroll
    for (int i = 0; i < 4; ++i)
#pragma unroll
        for (int j = 0; j < 4; ++j) acc[i][j] = 0.f;

    for (int p = 0; p < 2; ++p) {
        __syncthreads();
#pragma unroll
        for (int t = 0; t < 4; ++t) {
            const int idx = t * 256 + tid;
            const int m = idx >> 4, kv = idx & 15;
            float4 v = make_float4(0.f, 0.f, 0.f, 0.f);
            if (n0 + m < N_NODES)
                v = *(const float4*)(x + (size_t)(n0 + m) * N_FEAT + p * 64 + kv * 4);
            *(float4*)&xs[m][kv * 4] = v;
            *(float4*)&ws[m][kv * 4] =
                *(const float4*)(W + (size_t)(p * 64 + m) * N_HID + kv * 4);
        }
        __syncthreads();
#pragma unroll 2
        for (int k4 = 0; k4 < 16; ++k4) {
            float4 a[4], bb[4];
#pragma unroll
            for (int i = 0; i < 4; ++i)
                a[i] = *(const float4*)&xs[ty + 16 * i][k4 * 4];
#pragma unroll
            for (int j = 0; j < 4; ++j)
                bb[j] = *(const float4*)&ws[k4 * 4 + j][tx * 4];
#pragma unroll
            for (int i = 0; i < 4; ++i) {
                const float* ap = (const float*)&a[i];
#pragma unroll
                for (int j = 0; j < 4; ++j) {
                    const float* bp = (const float*)&bb[j];
#pragma unroll
                    for (int c = 0; c < 4; ++c)
                        acc[i][c] = fmaf(ap[j], bp[c], acc[i][c]);
                }
            }
        }
    }

    const float4 bias = *(const float4*)(b + tx * 4);
#pragma unroll
    for (int i = 0; i < 4; ++i) {
        const int node = n0 + ty + 16 * i;
        if (node < N_NODES) {
            float4 r;
            r.x = acc[i][0] + bias.x; r.y = acc[i][1] + bias.y;
            r.z = acc[i][2] + bias.z; r.w = acc[i][3] + bias.w;
            *(float4*)(h + (size_t)node * N_HID + tx * 4) = r;
        }
    }
}

// ---------------- scan stage 1: per-block (1024 elems) exclusive scan ----------
__global__ __launch_bounds__(256) void scan1_kernel(
    const int* __restrict__ deg, int* __restrict__ pref, int* __restrict__ bsum)
{
    __shared__ int tsum[256];
    const int base = blockIdx.x * 1024 + threadIdx.x * 4;
    int v[4];
#pragma unroll
    for (int j = 0; j < 4; ++j)
        v[j] = (base + j < N_NODES) ? deg[base + j] : 0;
    int run = 0;
#pragma unroll
    for (int j = 0; j < 4; ++j) { int t = v[j]; v[j] = run; run += t; }
    tsum[threadIdx.x] = run;
    __syncthreads();
    for (int off = 1; off < 256; off <<= 1) {
        int t = (threadIdx.x >= off) ? tsum[threadIdx.x - off] : 0;
        __syncthreads();
        tsum[threadIdx.x] += t;
        __syncthreads();
    }
    const int excl = (threadIdx.x > 0) ? tsum[threadIdx.x - 1] : 0;
#pragma unroll
    for (int j = 0; j < 4; ++j)
        if (base + j < N_NODES) pref[base + j] = v[j] + excl;
    if (threadIdx.x == 255) bsum[blockIdx.x] = tsum[255];
}

// ---- scan stages 2+3 merged: each block redoes the tiny 98-elem bsum scan
// in LDS (L2-hot), then streams row = pref + blockoffset ----
__global__ __launch_bounds__(256) void scan23_kernel(
    const int* __restrict__ pref, const int* __restrict__ bsum,
    int* __restrict__ rowp)
{
    __shared__ int sp[SCAN_NB];
    const int tid = threadIdx.x;
    __shared__ int sb[SCAN_NB];
    if (tid < SCAN_NB) sb[tid] = bsum[tid];
    __syncthreads();
    if (tid == 0) {
        int run = 0;
        for (int i = 0; i < SCAN_NB; ++i) { sp[i] = run; run += sb[i]; }
    }
    __syncthreads();
    const int stride = gridDim.x * blockDim.x;
    for (int i = blockIdx.x * blockDim.x + tid; i < N_NODES; i += stride)
        rowp[i] = pref[i] + sp[i >> 10];
}

// ---- CSR fill: no atomics (pos = row[d]+rank[e]); 6 dst-range passes so the
// ---- active csr/row window (~1.1 MB / 67 KB) stays L2-resident ----
__global__ __launch_bounds__(256) void fill_kernel(
    const int* __restrict__ ei, const int* __restrict__ rank,
    const int* __restrict__ rowp, int* __restrict__ csr)
{
    const int stride = gridDim.x * blockDim.x;
    const int tid0 = blockIdx.x * blockDim.x + threadIdx.x;
    for (int pass = 0; pass < NPASS; ++pass) {
        const int lo = pass * PRANGE;
        const int hi = lo + PRANGE;
        for (int e = tid0; e < N_EDGES; e += stride) {
            const int d = ei[N_EDGES + e];
            if (d >= lo && d < hi)
                csr[rowp[d] + rank[e]] = ei[e];
        }
    }
}

// ---- fused GIN layer: gather (CSR, wave-per-node, straight into LDS tile)
// + 2-GEMM MLP. Eliminates the agg global round-trip (50 MB/layer).
// h ping-pong: reads hin, writes hout (blocks read other blocks' rows).
// Gather edge loop: UNIFORM trip count so every __shfl source lane is active
// (ds_bpermute from an inactive lane is undefined — round-3 bug).
__global__ __launch_bounds__(256, 4) void gather_mlp_kernel(
    const float* __restrict__ hin, float* __restrict__ hout,
    const int* __restrict__ csr, const int* __restrict__ rowp,
    const int* __restrict__ deg,
    const float* __restrict__ W1, const float* __restrict__ b1,
    const float* __restrict__ W2, const float* __restrict__ b2)
{
    __shared__ float as[64][68];    // gathered tile, then z tile
    __shared__ float ws[64][68];    // W1, then W2
    const int tid = threadIdx.x;
    const int tx = tid & 15, ty = tid >> 4;
    const int lane = tid & 63, wave = tid >> 6;
    const int grp = lane >> 4, sub = lane & 15;
    const int n0 = blockIdx.x * 64;

    // stage W1 now; its load latency hides behind the gather
#pragma unroll
    for (int t = 0; t < 4; ++t) {
        const int idx = t * 256 + tid;
        const int m = idx >> 4, kv = idx & 15;
        *(float4*)&ws[m][kv * 4] = *(const float4*)(W1 + (size_t)m * N_HID + kv * 4);
    }

    // gather: wave w owns tile rows [w*16, w*16+16)
    for (int j = 0; j < 16; ++j) {
        const int node = n0 + wave * 16 + j;   // wave-uniform
        if (node < N_NODES) {
            const int un = __builtin_amdgcn_readfirstlane(node);
            const int lo = __builtin_amdgcn_readfirstlane(rowp[un]);
            const int n  = __builtin_amdgcn_readfirstlane(deg[un]);
            int eidx = 0;
            if (lane < n) eidx = csr[lo + lane];    // whole bucket, one load
            float ax = 0.f, ay = 0.f, az = 0.f, aw = 0.f;
            if (grp == 0) {
                const float4 a = *(const float4*)(hin + (size_t)un * N_HID + (sub << 2));
                ax += a.x; ay += a.y; az += a.z; aw += a.w;
            }
            for (int eb = 0; eb < n; eb += 8) {     // UNIFORM trip count
                const int j0 = eb + grp;
                const int j1 = j0 + 4;
                const int s0 = __shfl(eidx, j0, 64);
                const int s1 = __shfl(eidx, j1, 64);
                if (j0 < n) {
                    const float4 a = *(const float4*)(hin + (size_t)s0 * N_HID + (sub << 2));
                    ax += a.x; ay += a.y; az += a.z; aw += a.w;
                }
                if (j1 < n) {
                    const float4 a = *(const float4*)(hin + (size_t)s1 * N_HID + (sub << 2));
                    ax += a.x; ay += a.y; az += a.z; aw += a.w;
                }
            }
            ax += __shfl_xor(ax, 16, 64); ay += __shfl_xor(ay, 16, 64);
            az += __shfl_xor(az, 16, 64); aw += __shfl_xor(aw, 16, 64);
            ax += __shfl_xor(ax, 32, 64); ay += __shfl_xor(ay, 32, 64);
            az += __shfl_xor(az, 32, 64); aw += __shfl_xor(aw, 32, 64);
            if (grp == 0)
                *(float4*)&as[wave * 16 + j][sub << 2] = make_float4(ax, ay, az, aw);
        } else if (grp == 0) {
            *(float4*)&as[wave * 16 + j][sub << 2] = make_float4(0.f, 0.f, 0.f, 0.f);
        }
    }
    __syncthreads();

    // phase 1: z = relu(agg @ W1 + b1)
    float acc[4][4];
#pragma unroll
    for (int i = 0; i < 4; ++i)
#pragma unroll
        for (int j = 0; j < 4; ++j) acc[i][j] = 0.f;
#pragma unroll 2
    for (int k4 = 0; k4 < 16; ++k4) {
        float4 a[4], bb[4];
#pragma unroll
        for (int i = 0; i < 4; ++i)
            a[i] = *(const float4*)&as[ty + 16 * i][k4 * 4];
#pragma unroll
        for (int j = 0; j < 4; ++j)
            bb[j] = *(const float4*)&ws[k4 * 4 + j][tx * 4];
#pragma unroll
        for (int i = 0; i < 4; ++i) {
            const float* ap = (const float*)&a[i];
#pragma unroll
            for (int j = 0; j < 4; ++j) {
                const float* bp = (const float*)&bb[j];
#pragma unroll
                for (int c = 0; c < 4; ++c)
                    acc[i][c] = fmaf(ap[j], bp[c], acc[i][c]);
            }
        }
    }
    const float4 bias1 = *(const float4*)(b1 + tx * 4);
    float4 z[4];
#pragma unroll
    for (int i = 0; i < 4; ++i) {
        z[i].x = fmaxf(acc[i][0] + bias1.x, 0.f);
        z[i].y = fmaxf(acc[i][1] + bias1.y, 0.f);
        z[i].z = fmaxf(acc[i][2] + bias1.z, 0.f);
        z[i].w = fmaxf(acc[i][3] + bias1.w, 0.f);
    }
    __syncthreads();               // all phase-1 reads of as/ws done
#pragma unroll
    for (int i = 0; i < 4; ++i)
        *(float4*)&as[ty + 16 * i][tx * 4] = z[i];
#pragma unroll
    for (int t = 0; t < 4; ++t) {
        const int idx = t * 256 + tid;
        const int m = idx >> 4, kv = idx & 15;
        *(float4*)&ws[m][kv * 4] = *(const float4*)(W2 + (size_t)m * N_HID + kv * 4);
    }
    __syncthreads();

    // phase 2: h = relu(z @ W2 + b2)
#pragma unroll
    for (int i = 0; i < 4; ++i)
#pragma unroll
        for (int j = 0; j < 4; ++j) acc[i][j] = 0.f;
#pragma unroll 2
    for (int k4 = 0; k4 < 16; ++k4) {
        float4 a[4], bb[4];
#pragma unroll
        for (int i = 0; i < 4; ++i)
            a[i] = *(const float4*)&as[ty + 16 * i][k4 * 4];
#pragma unroll
        for (int j = 0; j < 4; ++j)
            bb[j] = *(const float4*)&ws[k4 * 4 + j][tx * 4];
#pragma unroll
        for (int i = 0; i < 4; ++i) {
            const float* ap = (const float*)&a[i];
#pragma unroll
            for (int j = 0; j < 4; ++j) {
                const float* bp = (const float*)&bb[j];
#pragma unroll
                for (int c = 0; c < 4; ++c)
                    acc[i][c] = fmaf(ap[j], bp[c], acc[i][c]);
            }
        }
    }
    const float4 bias2 = *(const float4*)(b2 + tx * 4);
#pragma unroll
    for (int i = 0; i < 4; ++i) {
        const int node = n0 + ty + 16 * i;
        if (node < N_NODES) {
            float4 r;
            r.x = fmaxf(acc[i][0] + bias2.x, 0.f);
            r.y = fmaxf(acc[i][1] + bias2.y, 0.f);
            r.z = fmaxf(acc[i][2] + bias2.z, 0.f);
            r.w = fmaxf(acc[i][3] + bias2.w, 0.f);
            *(float4*)(hout + (size_t)node * N_HID + tx * 4) = r;
        }
    }
}

// ---- fused pool+head: block per graph; wave 0 finishes post/ro/log_softmax
// in-register from the pooled row (g never hits global). ----
__global__ __launch_bounds__(256) void pool_head_kernel(
    const float* __restrict__ h, const int* __restrict__ batch,
    const float* __restrict__ Wp, const float* __restrict__ bp,
    const float* __restrict__ Wr, const float* __restrict__ br,
    float* __restrict__ out)
{
    const int graph = blockIdx.x;
    int l = 0, r = N_NODES;
    while (l < r) { int m = (l + r) >> 1; if (batch[m] < graph) l = m + 1; else r = m; }
    const int lo = l;
    r = N_NODES;
    while (l < r) { int m = (l + r) >> 1; if (batch[m] < graph + 1) l = m + 1; else r = m; }
    const int hi = l;

    const int lane = threadIdx.x & 63;
    const int wave = threadIdx.x >> 6;
    float acc = 0.0f;
    for (int i = lo + wave; i < hi; i += 4)
        acc += h[(size_t)i * N_HID + lane];
    __shared__ float sacc[4][N_HID];
    sacc[wave][lane] = acc;
    __syncthreads();
    if (wave != 0) return;

    const float gv = sacc[0][lane] + sacc[1][lane] + sacc[2][lane] + sacc[3][lane];
    float acc2 = bp[lane];
#pragma unroll
    for (int k = 0; k < N_HID; ++k) {
        const float gk = __int_as_float(
            __builtin_amdgcn_readlane(__float_as_int(gv), k));  // exec-ignoring
        acc2 = fmaf(gk, Wp[k * N_HID + lane], acc2);
    }
    const float y = fmaxf(acc2, 0.f);

    float logit = (lane < N_CLASS) ? br[lane] : 0.f;
#pragma unroll
    for (int k = 0; k < N_HID; ++k) {
        const float yk = __int_as_float(
            __builtin_amdgcn_readlane(__float_as_int(y), k));
        if (lane < N_CLASS)
            logit = fmaf(yk, Wr[k * N_CLASS + lane], logit);
    }

    __shared__ float slog[N_CLASS];
    if (lane < N_CLASS) slog[lane] = logit;
    // same-wave LDS RAW: compiler inserts the lgkmcnt wait
    if (lane < N_CLASS) {
        float m = -INFINITY;
#pragma unroll
        for (int c = 0; c < N_CLASS; ++c) m = fmaxf(m, slog[c]);
        float sum = 0.0f;
#pragma unroll
        for (int c = 0; c < N_CLASS; ++c) sum += expf(slog[c] - m);
        out[(size_t)graph * N_CLASS + lane] = logit - m - logf(sum);
    }
}

extern "C" void kernel_launch(void* const* d_in, const int* in_sizes, int n_in,
                              void* d_out, int out_size, void* d_ws, size_t ws_size,
                              hipStream_t stream)
{
    const float* x       = (const float*)d_in[0];
    const int*   ei      = (const int*)d_in[1];   // [2, E]: row0=src, row1=dst
    const int*   batch   = (const int*)d_in[2];
    const float* pre_w   = (const float*)d_in[3];
    const float* pre_b   = (const float*)d_in[4];
    const float* conv_w1 = (const float*)d_in[5];
    const float* conv_b1 = (const float*)d_in[6];
    const float* conv_w2 = (const float*)d_in[7];
    const float* conv_b2 = (const float*)d_in[8];
    const float* post_w  = (const float*)d_in[9];
    const float* post_b  = (const float*)d_in[10];
    const float* ro_w    = (const float*)d_in[11];
    const float* ro_b    = (const float*)d_in[12];
    float* out = (float*)d_out;

    // workspace layout (~59 MB, same budget as round 6)
    float* h0     = (float*)d_ws;                          // 6.4M f
    float* h1     = h0 + (size_t)N_NODES * N_HID;          // 6.4M f
    int*   deg    = (int*)(h1 + (size_t)N_NODES * N_HID);  // 100K i
    int*   rowp   = deg + N_NODES;                         // 100K i
    int*   pref   = rowp + N_NODES;                        // 100K i (scan temp)
    int*   bsum   = pref + N_NODES;                        // 128 i
    int*   csr    = bsum + 128;                            // 1.6M i
    int*   rank   = (int*)h1;   // alias: rank dead after fill; h1 first
                                // written by gather_mlp layer 1 (after fill)

    hipMemsetAsync(deg, 0, N_NODES * sizeof(int), stream);

    // CSR hist + pre GEMM overlapped in one dispatch
    pre_hist_kernel<<<HIST_NB + NTILES, 256, 0, stream>>>(
        x, pre_w, pre_b, h0, ei, deg, rank);

    scan1_kernel<<<SCAN_NB, 256, 0, stream>>>(deg, pref, bsum);
    scan23_kernel<<<128, 256, 0, stream>>>(pref, bsum, rowp);
    fill_kernel<<<2048, 256, 0, stream>>>(ei, rank, rowp, csr);

    // 3 fused GIN layers, h ping-pong h0 -> h1 -> h0 -> h1
    gather_mlp_kernel<<<NTILES, 256, 0, stream>>>(
        h0, h1, csr, rowp, deg,
        conv_w1, conv_b1, conv_w2, conv_b2);
    gather_mlp_kernel<<<NTILES, 256, 0, stream>>>(
        h1, h0, csr, rowp, deg,
        conv_w1 + N_HID * N_HID, conv_b1 + N_HID,
        conv_w2 + N_HID * N_HID, conv_b2 + N_HID);
    gather_mlp_kernel<<<NTILES, 256, 0, stream>>>(
        h0, h1, csr, rowp, deg,
        conv_w1 + 2 * N_HID * N_HID, conv_b1 + 2 * N_HID,
        conv_w2 + 2 * N_HID * N_HID, conv_b2 + 2 * N_HID);

    pool_head_kernel<<<N_GRAPHS, 256, 0, stream>>>(
        h1, batch, post_w, post_b, ro_w, ro_b, out);
}

// Round 8
// 539.115 us; speedup vs baseline: 1.0013x; 1.0013x over previous
//
#include <hip/hip_runtime.h>
#include <math.h>

#define N_NODES  100000
#define N_FEAT   128
#define N_HID    64
#define N_CLASS  10
#define N_GRAPHS 1000
#define N_EDGES  1600000
#define SCAN_NB  98        // ceil(100000/1024)
#define NPASS    6
#define PRANGE   16667     // ceil(100000/6)
#define NTILES   1563      // ceil(100000/64)
#define HIST_NB  2048

// ---- bf16 helpers: h is stored bf16 (row = 128 B) to halve the gather's
// L2-miss traffic (round-7 counters: FETCH 186 MB vs 25.6 MB array — per-XCD
// L2 re-fetch wall). All arithmetic stays fp32.
__device__ __forceinline__ float bflo(unsigned u) { return __uint_as_float(u << 16); }
__device__ __forceinline__ float bfhi(unsigned u) { return __uint_as_float(u & 0xffff0000u); }
__device__ __forceinline__ unsigned bf_rne(float f) {
    unsigned u = __float_as_uint(f);
    return (u + 0x7fffu + ((u >> 16) & 1u)) >> 16;
}
__device__ __forceinline__ unsigned pack2(float a, float b) {
    return bf_rne(a) | (bf_rne(b) << 16);
}

// ---- fused: blocks [0,HIST_NB) = degree histogram (rank = atomic return);
// ---- blocks [HIST_NB,...) = pre GEMM h0 = x@pre_w + pre_b (bf16 out).
__global__ __launch_bounds__(256, 4) void pre_hist_kernel(
    const float* __restrict__ x, const float* __restrict__ W,
    const float* __restrict__ b, uint2* __restrict__ h,
    const int* __restrict__ ei, int* __restrict__ deg, int* __restrict__ rank)
{
    __shared__ float xs[64][68];    // x half-tile [m][kk]
    __shared__ float ws[64][68];    // W half     [kk][c]
    const int tid = threadIdx.x;

    if (blockIdx.x < HIST_NB) {
        const int stride = HIST_NB * 256;
        for (int e = blockIdx.x * 256 + tid; e < N_EDGES; e += stride)
            rank[e] = atomicAdd(&deg[ei[N_EDGES + e]], 1);
        return;
    }

    const int tx = tid & 15, ty = tid >> 4;
    const int n0 = (blockIdx.x - HIST_NB) * 64;

    float acc[4][4];
#pragma unroll
    for (int i = 0; i < 4; ++i)
#pragma unroll
        for (int j = 0; j < 4; ++j) acc[i][j] = 0.f;

    for (int p = 0; p < 2; ++p) {
        __syncthreads();
#pragma unroll
        for (int t = 0; t < 4; ++t) {
            const int idx = t * 256 + tid;
            const int m = idx >> 4, kv = idx & 15;
            float4 v = make_float4(0.f, 0.f, 0.f, 0.f);
            if (n0 + m < N_NODES)
                v = *(const float4*)(x + (size_t)(n0 + m) * N_FEAT + p * 64 + kv * 4);
            *(float4*)&xs[m][kv * 4] = v;
            *(float4*)&ws[m][kv * 4] =
                *(const float4*)(W + (size_t)(p * 64 + m) * N_HID + kv * 4);
        }
        __syncthreads();
#pragma unroll 2
        for (int k4 = 0; k4 < 16; ++k4) {
            float4 a[4], bb[4];
#pragma unroll
            for (int i = 0; i < 4; ++i)
                a[i] = *(const float4*)&xs[ty + 16 * i][k4 * 4];
#pragma unroll
            for (int j = 0; j < 4; ++j)
                bb[j] = *(const float4*)&ws[k4 * 4 + j][tx * 4];
#pragma unroll
            for (int i = 0; i < 4; ++i) {
                const float* ap = (const float*)&a[i];
#pragma unroll
                for (int j = 0; j < 4; ++j) {
                    const float* bp = (const float*)&bb[j];
#pragma unroll
                    for (int c = 0; c < 4; ++c)
                        acc[i][c] = fmaf(ap[j], bp[c], acc[i][c]);
                }
            }
        }
    }

    const float4 bias = *(const float4*)(b + tx * 4);
#pragma unroll
    for (int i = 0; i < 4; ++i) {
        const int node = n0 + ty + 16 * i;
        if (node < N_NODES) {
            h[(size_t)node * 16 + tx] = make_uint2(
                pack2(acc[i][0] + bias.x, acc[i][1] + bias.y),
                pack2(acc[i][2] + bias.z, acc[i][3] + bias.w));
        }
    }
}

// ---------------- scan stage 1: per-block (1024 elems) exclusive scan ----------
__global__ __launch_bounds__(256) void scan1_kernel(
    const int* __restrict__ deg, int* __restrict__ pref, int* __restrict__ bsum)
{
    __shared__ int tsum[256];
    const int base = blockIdx.x * 1024 + threadIdx.x * 4;
    int v[4];
#pragma unroll
    for (int j = 0; j < 4; ++j)
        v[j] = (base + j < N_NODES) ? deg[base + j] : 0;
    int run = 0;
#pragma unroll
    for (int j = 0; j < 4; ++j) { int t = v[j]; v[j] = run; run += t; }
    tsum[threadIdx.x] = run;
    __syncthreads();
    for (int off = 1; off < 256; off <<= 1) {
        int t = (threadIdx.x >= off) ? tsum[threadIdx.x - off] : 0;
        __syncthreads();
        tsum[threadIdx.x] += t;
        __syncthreads();
    }
    const int excl = (threadIdx.x > 0) ? tsum[threadIdx.x - 1] : 0;
#pragma unroll
    for (int j = 0; j < 4; ++j)
        if (base + j < N_NODES) pref[base + j] = v[j] + excl;
    if (threadIdx.x == 255) bsum[blockIdx.x] = tsum[255];
}

// ---- scan stages 2+3 merged ----
__global__ __launch_bounds__(256) void scan23_kernel(
    const int* __restrict__ pref, const int* __restrict__ bsum,
    int* __restrict__ rowp)
{
    __shared__ int sp[SCAN_NB];
    __shared__ int sb[SCAN_NB];
    const int tid = threadIdx.x;
    if (tid < SCAN_NB) sb[tid] = bsum[tid];
    __syncthreads();
    if (tid == 0) {
        int run = 0;
        for (int i = 0; i < SCAN_NB; ++i) { sp[i] = run; run += sb[i]; }
    }
    __syncthreads();
    const int stride = gridDim.x * blockDim.x;
    for (int i = blockIdx.x * blockDim.x + tid; i < N_NODES; i += stride)
        rowp[i] = pref[i] + sp[i >> 10];
}

// ---- CSR fill: no atomics; 6 dst-range passes keep csr/row window L2-resident
__global__ __launch_bounds__(256) void fill_kernel(
    const int* __restrict__ ei, const int* __restrict__ rank,
    const int* __restrict__ rowp, int* __restrict__ csr)
{
    const int stride = gridDim.x * blockDim.x;
    const int tid0 = blockIdx.x * blockDim.x + threadIdx.x;
    for (int pass = 0; pass < NPASS; ++pass) {
        const int lo = pass * PRANGE;
        const int hi = lo + PRANGE;
        for (int e = tid0; e < N_EDGES; e += stride) {
            const int d = ei[N_EDGES + e];
            if (d >= lo && d < hi)
                csr[rowp[d] + rank[e]] = ei[e];
        }
    }
}

// ---- fused GIN layer: bf16 gather into LDS (fp32 accum) + fp32 2-GEMM MLP,
// bf16 out. h ping-pong hin -> hout. Gather edge loop: UNIFORM trip count so
// every __shfl source lane is active (ds_bpermute from an inactive lane is
// undefined — round-3 bug).
__global__ __launch_bounds__(256, 4) void gather_mlp_kernel(
    const uint2* __restrict__ hin, uint2* __restrict__ hout,
    const int* __restrict__ csr, const int* __restrict__ rowp,
    const int* __restrict__ deg,
    const float* __restrict__ W1, const float* __restrict__ b1,
    const float* __restrict__ W2, const float* __restrict__ b2)
{
    __shared__ float as[64][68];    // gathered tile, then z tile
    __shared__ float ws[64][68];    // W1, then W2
    const int tid = threadIdx.x;
    const int tx = tid & 15, ty = tid >> 4;
    const int lane = tid & 63, wave = tid >> 6;
    const int grp = lane >> 4, sub = lane & 15;
    const int n0 = blockIdx.x * 64;

    // stage W1 now; its load latency hides behind the gather
#pragma unroll
    for (int t = 0; t < 4; ++t) {
        const int idx = t * 256 + tid;
        const int m = idx >> 4, kv = idx & 15;
        *(float4*)&ws[m][kv * 4] = *(const float4*)(W1 + (size_t)m * N_HID + kv * 4);
    }

    // gather: wave w owns tile rows [w*16, w*16+16); row = 16 uint2 (128 B)
    for (int j = 0; j < 16; ++j) {
        const int node = n0 + wave * 16 + j;   // wave-uniform
        if (node < N_NODES) {
            const int un = __builtin_amdgcn_readfirstlane(node);
            const int lo = __builtin_amdgcn_readfirstlane(rowp[un]);
            const int n  = __builtin_amdgcn_readfirstlane(deg[un]);
            int eidx = 0;
            if (lane < n) eidx = csr[lo + lane];    // whole bucket, one load
            float ax = 0.f, ay = 0.f, az = 0.f, aw = 0.f;
            if (grp == 0) {
                const uint2 a = hin[(size_t)un * 16 + sub];
                ax += bflo(a.x); ay += bfhi(a.x);
                az += bflo(a.y); aw += bfhi(a.y);
            }
            for (int eb = 0; eb < n; eb += 8) {     // UNIFORM trip count
                const int j0 = eb + grp;
                const int j1 = j0 + 4;
                const int s0 = __shfl(eidx, j0, 64);
                const int s1 = __shfl(eidx, j1, 64);
                if (j0 < n) {
                    const uint2 a = hin[(size_t)s0 * 16 + sub];
                    ax += bflo(a.x); ay += bfhi(a.x);
                    az += bflo(a.y); aw += bfhi(a.y);
                }
                if (j1 < n) {
                    const uint2 a = hin[(size_t)s1 * 16 + sub];
                    ax += bflo(a.x); ay += bfhi(a.x);
                    az += bflo(a.y); aw += bfhi(a.y);
                }
            }
            ax += __shfl_xor(ax, 16, 64); ay += __shfl_xor(ay, 16, 64);
            az += __shfl_xor(az, 16, 64); aw += __shfl_xor(aw, 16, 64);
            ax += __shfl_xor(ax, 32, 64); ay += __shfl_xor(ay, 32, 64);
            az += __shfl_xor(az, 32, 64); aw += __shfl_xor(aw, 32, 64);
            if (grp == 0)
                *(float4*)&as[wave * 16 + j][sub << 2] = make_float4(ax, ay, az, aw);
        } else if (grp == 0) {
            *(float4*)&as[wave * 16 + j][sub << 2] = make_float4(0.f, 0.f, 0.f, 0.f);
        }
    }
    __syncthreads();

    // phase 1: z = relu(agg @ W1 + b1)
    float acc[4][4];
#pragma unroll
    for (int i = 0; i < 4; ++i)
#pragma unroll
        for (int j = 0; j < 4; ++j) acc[i][j] = 0.f;
#pragma unroll 2
    for (int k4 = 0; k4 < 16; ++k4) {
        float4 a[4], bb[4];
#pragma unroll
        for (int i = 0; i < 4; ++i)
            a[i] = *(const float4*)&as[ty + 16 * i][k4 * 4];
#pragma unroll
        for (int j = 0; j < 4; ++j)
            bb[j] = *(const float4*)&ws[k4 * 4 + j][tx * 4];
#pragma unroll
        for (int i = 0; i < 4; ++i) {
            const float* ap = (const float*)&a[i];
#pragma unroll
            for (int j = 0; j < 4; ++j) {
                const float* bp = (const float*)&bb[j];
#pragma unroll
                for (int c = 0; c < 4; ++c)
                    acc[i][c] = fmaf(ap[j], bp[c], acc[i][c]);
            }
        }
    }
    const float4 bias1 = *(const float4*)(b1 + tx * 4);
    float4 z[4];
#pragma unroll
    for (int i = 0; i < 4; ++i) {
        z[i].x = fmaxf(acc[i][0] + bias1.x, 0.f);
        z[i].y = fmaxf(acc[i][1] + bias1.y, 0.f);
        z[i].z = fmaxf(acc[i][2] + bias1.z, 0.f);
        z[i].w = fmaxf(acc[i][3] + bias1.w, 0.f);
    }
    __syncthreads();               // all phase-1 reads of as/ws done
#pragma unroll
    for (int i = 0; i < 4; ++i)
        *(float4*)&as[ty + 16 * i][tx * 4] = z[i];
#pragma unroll
    for (int t = 0; t < 4; ++t) {
        const int idx = t * 256 + tid;
        const int m = idx >> 4, kv = idx & 15;
        *(float4*)&ws[m][kv * 4] = *(const float4*)(W2 + (size_t)m * N_HID + kv * 4);
    }
    __syncthreads();

    // phase 2: h = relu(z @ W2 + b2), bf16 out
#pragma unroll
    for (int i = 0; i < 4; ++i)
#pragma unroll
        for (int j = 0; j < 4; ++j) acc[i][j] = 0.f;
#pragma unroll 2
    for (int k4 = 0; k4 < 16; ++k4) {
        float4 a[4], bb[4];
#pragma unroll
        for (int i = 0; i < 4; ++i)
            a[i] = *(const float4*)&as[ty + 16 * i][k4 * 4];
#pragma unroll
        for (int j = 0; j < 4; ++j)
            bb[j] = *(const float4*)&ws[k4 * 4 + j][tx * 4];
#pragma unroll
        for (int i = 0; i < 4; ++i) {
            const float* ap = (const float*)&a[i];
#pragma unroll
            for (int j = 0; j < 4; ++j) {
                const float* bp = (const float*)&bb[j];
#pragma unroll
                for (int c = 0; c < 4; ++c)
                    acc[i][c] = fmaf(ap[j], bp[c], acc[i][c]);
            }
        }
    }
    const float4 bias2 = *(const float4*)(b2 + tx * 4);
#pragma unroll
    for (int i = 0; i < 4; ++i) {
        const int node = n0 + ty + 16 * i;
        if (node < N_NODES) {
            hout[(size_t)node * 16 + tx] = make_uint2(
                pack2(fmaxf(acc[i][0] + bias2.x, 0.f),
                      fmaxf(acc[i][1] + bias2.y, 0.f)),
                pack2(fmaxf(acc[i][2] + bias2.z, 0.f),
                      fmaxf(acc[i][3] + bias2.w, 0.f)));
        }
    }
}

// ---- fused pool+head: block per graph; wave 0 finishes post/ro/log_softmax
// in-register from the pooled row. h is bf16. ----
__global__ __launch_bounds__(256) void pool_head_kernel(
    const unsigned short* __restrict__ h, const int* __restrict__ batch,
    const float* __restrict__ Wp, const float* __restrict__ bp,
    const float* __restrict__ Wr, const float* __restrict__ br,
    float* __restrict__ out)
{
    const int graph = blockIdx.x;
    int l = 0, r = N_NODES;
    while (l < r) { int m = (l + r) >> 1; if (batch[m] < graph) l = m + 1; else r = m; }
    const int lo = l;
    r = N_NODES;
    while (l < r) { int m = (l + r) >> 1; if (batch[m] < graph + 1) l = m + 1; else r = m; }
    const int hi = l;

    const int lane = threadIdx.x & 63;
    const int wave = threadIdx.x >> 6;
    float acc = 0.0f;
    for (int i = lo + wave; i < hi; i += 4)
        acc += __uint_as_float(((unsigned)h[(size_t)i * N_HID + lane]) << 16);
    __shared__ float sacc[4][N_HID];
    sacc[wave][lane] = acc;
    __syncthreads();
    if (wave != 0) return;

    const float gv = sacc[0][lane] + sacc[1][lane] + sacc[2][lane] + sacc[3][lane];
    float acc2 = bp[lane];
#pragma unroll
    for (int k = 0; k < N_HID; ++k) {
        const float gk = __int_as_float(
            __builtin_amdgcn_readlane(__float_as_int(gv), k));  // exec-ignoring
        acc2 = fmaf(gk, Wp[k * N_HID + lane], acc2);
    }
    const float y = fmaxf(acc2, 0.f);

    float logit = (lane < N_CLASS) ? br[lane] : 0.f;
#pragma unroll
    for (int k = 0; k < N_HID; ++k) {
        const float yk = __int_as_float(
            __builtin_amdgcn_readlane(__float_as_int(y), k));
        if (lane < N_CLASS)
            logit = fmaf(yk, Wr[k * N_CLASS + lane], logit);
    }

    __shared__ float slog[N_CLASS];
    if (lane < N_CLASS) slog[lane] = logit;
    if (lane < N_CLASS) {
        float m = -INFINITY;
#pragma unroll
        for (int c = 0; c < N_CLASS; ++c) m = fmaxf(m, slog[c]);
        float sum = 0.0f;
#pragma unroll
        for (int c = 0; c < N_CLASS; ++c) sum += expf(slog[c] - m);
        out[(size_t)graph * N_CLASS + lane] = logit - m - logf(sum);
    }
}

extern "C" void kernel_launch(void* const* d_in, const int* in_sizes, int n_in,
                              void* d_out, int out_size, void* d_ws, size_t ws_size,
                              hipStream_t stream)
{
    const float* x       = (const float*)d_in[0];
    const int*   ei      = (const int*)d_in[1];   // [2, E]: row0=src, row1=dst
    const int*   batch   = (const int*)d_in[2];
    const float* pre_w   = (const float*)d_in[3];
    const float* pre_b   = (const float*)d_in[4];
    const float* conv_w1 = (const float*)d_in[5];
    const float* conv_b1 = (const float*)d_in[6];
    const float* conv_w2 = (const float*)d_in[7];
    const float* conv_b2 = (const float*)d_in[8];
    const float* post_w  = (const float*)d_in[9];
    const float* post_b  = (const float*)d_in[10];
    const float* ro_w    = (const float*)d_in[11];
    const float* ro_b    = (const float*)d_in[12];
    float* out = (float*)d_out;

    // workspace layout (~33 MB)
    uint2* h0     = (uint2*)d_ws;                          // 100K * 16 uint2 = 12.8 MB
    uint2* h1     = h0 + (size_t)N_NODES * 16;             // 12.8 MB
    int*   deg    = (int*)(h1 + (size_t)N_NODES * 16);     // 100K i
    int*   rowp   = deg + N_NODES;                         // 100K i
    int*   pref   = rowp + N_NODES;                        // 100K i (scan temp)
    int*   bsum   = pref + N_NODES;                        // 128 i
    int*   csr    = bsum + 128;                            // 1.6M i
    int*   rank   = (int*)h1;   // alias: rank (6.4 MB) dead after fill; h1
                                // first written by gather_mlp layer 1

    hipMemsetAsync(deg, 0, N_NODES * sizeof(int), stream);

    // CSR hist + pre GEMM overlapped in one dispatch
    pre_hist_kernel<<<HIST_NB + NTILES, 256, 0, stream>>>(
        x, pre_w, pre_b, h0, ei, deg, rank);

    scan1_kernel<<<SCAN_NB, 256, 0, stream>>>(deg, pref, bsum);
    scan23_kernel<<<128, 256, 0, stream>>>(pref, bsum, rowp);
    fill_kernel<<<2048, 256, 0, stream>>>(ei, rank, rowp, csr);

    // 3 fused GIN layers, h ping-pong h0 -> h1 -> h0 -> h1
    gather_mlp_kernel<<<NTILES, 256, 0, stream>>>(
        h0, h1, csr, rowp, deg,
        conv_w1, conv_b1, conv_w2, conv_b2);
    gather_mlp_kernel<<<NTILES, 256, 0, stream>>>(
        h1, h0, csr, rowp, deg,
        conv_w1 + N_HID * N_HID, conv_b1 + N_HID,
        conv_w2 + N_HID * N_HID, conv_b2 + N_HID);
    gather_mlp_kernel<<<NTILES, 256, 0, stream>>>(
        h0, h1, csr, rowp, deg,
        conv_w1 + 2 * N_HID * N_HID, conv_b1 + 2 * N_HID,
        conv_w2 + 2 * N_HID * N_HID, conv_b2 + 2 * N_HID);

    pool_head_kernel<<<N_GRAPHS, 256, 0, stream>>>(
        (const unsigned short*)h1, batch, post_w, post_b, ro_w, ro_b, out);
}

// Round 9
// 531.672 us; speedup vs baseline: 1.0153x; 1.0140x over previous
//
#include <hip/hip_runtime.h>
#include <math.h>

#define N_NODES  100000
#define N_FEAT   128
#define N_HID    64
#define N_CLASS  10
#define N_GRAPHS 1000
#define N_EDGES  1600000
#define NTILES   1563      // ceil(100000/64)   (pre kernel, 64-node tiles)
#define BLK_N    128       // gather_mlp tile
#define NT2      782       // ceil(100000/128)
#define HF_PASS  8
#define HF_RANGE 12500     // 100000/8; csr window 3.2 MB < 4 MB/XCD L2
#define CSR_STRIDE 64      // fixed bucket per node; P(deg>=64)~1e-20 @ Poisson(16)

// ---- bf16 helpers: h stored bf16 (row = 128 B); all arithmetic fp32.
__device__ __forceinline__ float bflo(unsigned u) { return __uint_as_float(u << 16); }
__device__ __forceinline__ float bfhi(unsigned u) { return __uint_as_float(u & 0xffff0000u); }
__device__ __forceinline__ unsigned bf_rne(float f) {
    unsigned u = __float_as_uint(f);
    return (u + 0x7fffu + ((u >> 16) & 1u)) >> 16;
}
__device__ __forceinline__ unsigned pack2(float a, float b) {
    return bf_rne(a) | (bf_rne(b) << 16);
}

// ---- pre: h0 = x @ pre_w + pre_b (bf16 out). Standalone: round-8 fusion
// with hist cost hist 40 us of occupancy (LDS tax on atomic-latency-bound
// blocks). 64-node tile, K split in two halves, 34.8 KB LDS, 4 blocks/CU.
__global__ __launch_bounds__(256, 4) void pre_kernel(
    const float* __restrict__ x, const float* __restrict__ W,
    const float* __restrict__ b, uint2* __restrict__ h)
{
    __shared__ float xs[64][68];
    __shared__ float ws[64][68];
    const int tid = threadIdx.x;
    const int tx = tid & 15, ty = tid >> 4;
    const int n0 = blockIdx.x * 64;

    float acc[4][4];
#pragma unroll
    for (int i = 0; i < 4; ++i)
#pragma unroll
        for (int j = 0; j < 4; ++j) acc[i][j] = 0.f;

    for (int p = 0; p < 2; ++p) {
        __syncthreads();
#pragma unroll
        for (int t = 0; t < 4; ++t) {
            const int idx = t * 256 + tid;
            const int m = idx >> 4, kv = idx & 15;
            float4 v = make_float4(0.f, 0.f, 0.f, 0.f);
            if (n0 + m < N_NODES)
                v = *(const float4*)(x + (size_t)(n0 + m) * N_FEAT + p * 64 + kv * 4);
            *(float4*)&xs[m][kv * 4] = v;
            *(float4*)&ws[m][kv * 4] =
                *(const float4*)(W + (size_t)(p * 64 + m) * N_HID + kv * 4);
        }
        __syncthreads();
#pragma unroll 2
        for (int k4 = 0; k4 < 16; ++k4) {
            float4 a[4], bb[4];
#pragma unroll
            for (int i = 0; i < 4; ++i)
                a[i] = *(const float4*)&xs[ty + 16 * i][k4 * 4];
#pragma unroll
            for (int j = 0; j < 4; ++j)
                bb[j] = *(const float4*)&ws[k4 * 4 + j][tx * 4];
#pragma unroll
            for (int i = 0; i < 4; ++i) {
                const float* ap = (const float*)&a[i];
#pragma unroll
                for (int j = 0; j < 4; ++j) {
                    const float* bp = (const float*)&bb[j];
#pragma unroll
                    for (int c = 0; c < 4; ++c)
                        acc[i][c] = fmaf(ap[j], bp[c], acc[i][c]);
                }
            }
        }
    }

    const float4 bias = *(const float4*)(b + tx * 4);
#pragma unroll
    for (int i = 0; i < 4; ++i) {
        const int node = n0 + ty + 16 * i;
        if (node < N_NODES) {
            h[(size_t)node * 16 + tx] = make_uint2(
                pack2(acc[i][0] + bias.x, acc[i][1] + bias.y),
                pack2(acc[i][2] + bias.z, acc[i][3] + bias.w));
        }
    }
}

// ---- hist+fill in ONE kernel, fixed-stride CSR, no scan, no rank array.
// p = atomicAdd(deg[d]) gives the slot; 8 dst-range passes keep the active
// csr window (3.2 MB) + deg window (50 KB) L2-resident (round-2 writeback
// thrash lesson). dst re-read 8x is L3-served.
__global__ __launch_bounds__(256) void hist_fill_kernel(
    const int* __restrict__ ei, int* __restrict__ deg, int* __restrict__ csr)
{
    const int stride = gridDim.x * blockDim.x;
    const int tid0 = blockIdx.x * blockDim.x + threadIdx.x;
    const int4* dst4 = (const int4*)(ei + N_EDGES);
    for (int pass = 0; pass < HF_PASS; ++pass) {
        const int lo = pass * HF_RANGE;
        const int hi = lo + HF_RANGE;
        for (int q = tid0; q < N_EDGES / 4; q += stride) {
            const int4 d = dst4[q];
            const int e0 = q * 4;
            if (d.x >= lo && d.x < hi) {
                int p = atomicAdd(&deg[d.x], 1);
                if (p < CSR_STRIDE) csr[d.x * CSR_STRIDE + p] = ei[e0];
            }
            if (d.y >= lo && d.y < hi) {
                int p = atomicAdd(&deg[d.y], 1);
                if (p < CSR_STRIDE) csr[d.y * CSR_STRIDE + p] = ei[e0 + 1];
            }
            if (d.z >= lo && d.z < hi) {
                int p = atomicAdd(&deg[d.z], 1);
                if (p < CSR_STRIDE) csr[d.z * CSR_STRIDE + p] = ei[e0 + 2];
            }
            if (d.w >= lo && d.w < hi) {
                int p = atomicAdd(&deg[d.w], 1);
                if (p < CSR_STRIDE) csr[d.w * CSR_STRIDE + p] = ei[e0 + 3];
            }
        }
    }
}

// ---- fused GIN layer, 512 threads / 128-node tile: bf16 gather into LDS
// (fp32 accum) + fp32 2-GEMM MLP, bf16 out. LDS 52.2 KB -> 3 blocks/CU x 8
// waves = 24 waves/CU (75% occ, vs 33% in the 256-thread version — the
// gather is latency-bound, more independent chains in flight).
// Gather edge loop: UNIFORM trip count so every __shfl source lane is active
// (ds_bpermute from an inactive lane is undefined — round-3 bug).
__global__ __launch_bounds__(512, 6) void gather_mlp_kernel(
    const uint2* __restrict__ hin, uint2* __restrict__ hout,
    const int* __restrict__ csr, const int* __restrict__ deg,
    const float* __restrict__ W1, const float* __restrict__ b1,
    const float* __restrict__ W2, const float* __restrict__ b2)
{
    __shared__ float as[BLK_N][68];   // gathered tile, then z tile
    __shared__ float ws[64][68];      // W1, then W2
    const int tid = threadIdx.x;
    const int tx = tid & 15, ty = tid >> 4;       // ty 0..31
    const int lane = tid & 63, wave = tid >> 6;   // wave 0..7
    const int grp = lane >> 4, sub = lane & 15;
    const int n0 = blockIdx.x * BLK_N;

    // stage W1 now; latency hides behind the gather
#pragma unroll
    for (int t = 0; t < 2; ++t) {
        const int idx = t * 512 + tid;
        const int m = idx >> 4, kv = idx & 15;
        *(float4*)&ws[m][kv * 4] = *(const float4*)(W1 + (size_t)m * N_HID + kv * 4);
    }

    // gather: wave w owns tile rows [w*16, w*16+16)
    for (int j = 0; j < 16; ++j) {
        const int node = n0 + wave * 16 + j;   // wave-uniform
        if (node < N_NODES) {
            const int un = __builtin_amdgcn_readfirstlane(node);
            int n = __builtin_amdgcn_readfirstlane(deg[un]);
            n = n > CSR_STRIDE ? CSR_STRIDE : n;
            int eidx = 0;
            if (lane < n) eidx = csr[un * CSR_STRIDE + lane];  // bucket, one load
            float ax = 0.f, ay = 0.f, az = 0.f, aw = 0.f;
            if (grp == 0) {
                const uint2 a = hin[(size_t)un * 16 + sub];
                ax += bflo(a.x); ay += bfhi(a.x);
                az += bflo(a.y); aw += bfhi(a.y);
            }
            for (int eb = 0; eb < n; eb += 8) {     // UNIFORM trip count
                const int j0 = eb + grp;
                const int j1 = j0 + 4;
                const int s0 = __shfl(eidx, j0, 64);
                const int s1 = __shfl(eidx, j1, 64);
                if (j0 < n) {
                    const uint2 a = hin[(size_t)s0 * 16 + sub];
                    ax += bflo(a.x); ay += bfhi(a.x);
                    az += bflo(a.y); aw += bfhi(a.y);
                }
                if (j1 < n) {
                    const uint2 a = hin[(size_t)s1 * 16 + sub];
                    ax += bflo(a.x); ay += bfhi(a.x);
                    az += bflo(a.y); aw += bfhi(a.y);
                }
            }
            ax += __shfl_xor(ax, 16, 64); ay += __shfl_xor(ay, 16, 64);
            az += __shfl_xor(az, 16, 64); aw += __shfl_xor(aw, 16, 64);
            ax += __shfl_xor(ax, 32, 64); ay += __shfl_xor(ay, 32, 64);
            az += __shfl_xor(az, 32, 64); aw += __shfl_xor(aw, 32, 64);
            if (grp == 0)
                *(float4*)&as[wave * 16 + j][sub << 2] = make_float4(ax, ay, az, aw);
        } else if (grp == 0) {
            *(float4*)&as[wave * 16 + j][sub << 2] = make_float4(0.f, 0.f, 0.f, 0.f);
        }
    }
    __syncthreads();

    // phase 1: z = relu(agg @ W1 + b1); rows ty + 32*i
    float acc[4][4];
#pragma unroll
    for (int i = 0; i < 4; ++i)
#pragma unroll
        for (int j = 0; j < 4; ++j) acc[i][j] = 0.f;
#pragma unroll 2
    for (int k4 = 0; k4 < 16; ++k4) {
        float4 a[4], bb[4];
#pragma unroll
        for (int i = 0; i < 4; ++i)
            a[i] = *(const float4*)&as[ty + 32 * i][k4 * 4];
#pragma unroll
        for (int j = 0; j < 4; ++j)
            bb[j] = *(const float4*)&ws[k4 * 4 + j][tx * 4];
#pragma unroll
        for (int i = 0; i < 4; ++i) {
            const float* ap = (const float*)&a[i];
#pragma unroll
            for (int j = 0; j < 4; ++j) {
                const float* bp = (const float*)&bb[j];
#pragma unroll
                for (int c = 0; c < 4; ++c)
                    acc[i][c] = fmaf(ap[j], bp[c], acc[i][c]);
            }
        }
    }
    const float4 bias1 = *(const float4*)(b1 + tx * 4);
    float4 z[4];
#pragma unroll
    for (int i = 0; i < 4; ++i) {
        z[i].x = fmaxf(acc[i][0] + bias1.x, 0.f);
        z[i].y = fmaxf(acc[i][1] + bias1.y, 0.f);
        z[i].z = fmaxf(acc[i][2] + bias1.z, 0.f);
        z[i].w = fmaxf(acc[i][3] + bias1.w, 0.f);
    }
    __syncthreads();               // all phase-1 reads of as/ws done
#pragma unroll
    for (int i = 0; i < 4; ++i)
        *(float4*)&as[ty + 32 * i][tx * 4] = z[i];
#pragma unroll
    for (int t = 0; t < 2; ++t) {
        const int idx = t * 512 + tid;
        const int m = idx >> 4, kv = idx & 15;
        *(float4*)&ws[m][kv * 4] = *(const float4*)(W2 + (size_t)m * N_HID + kv * 4);
    }
    __syncthreads();

    // phase 2: h = relu(z @ W2 + b2), bf16 out
#pragma unroll
    for (int i = 0; i < 4; ++i)
#pragma unroll
        for (int j = 0; j < 4; ++j) acc[i][j] = 0.f;
#pragma unroll 2
    for (int k4 = 0; k4 < 16; ++k4) {
        float4 a[4], bb[4];
#pragma unroll
        for (int i = 0; i < 4; ++i)
            a[i] = *(const float4*)&as[ty + 32 * i][k4 * 4];
#pragma unroll
        for (int j = 0; j < 4; ++j)
            bb[j] = *(const float4*)&ws[k4 * 4 + j][tx * 4];
#pragma unroll
        for (int i = 0; i < 4; ++i) {
            const float* ap = (const float*)&a[i];
#pragma unroll
            for (int j = 0; j < 4; ++j) {
                const float* bp = (const float*)&bb[j];
#pragma unroll
                for (int c = 0; c < 4; ++c)
                    acc[i][c] = fmaf(ap[j], bp[c], acc[i][c]);
            }
        }
    }
    const float4 bias2 = *(const float4*)(b2 + tx * 4);
#pragma unroll
    for (int i = 0; i < 4; ++i) {
        const int node = n0 + ty + 32 * i;
        if (node < N_NODES) {
            hout[(size_t)node * 16 + tx] = make_uint2(
                pack2(fmaxf(acc[i][0] + bias2.x, 0.f),
                      fmaxf(acc[i][1] + bias2.y, 0.f)),
                pack2(fmaxf(acc[i][2] + bias2.z, 0.f),
                      fmaxf(acc[i][3] + bias2.w, 0.f)));
        }
    }
}

// ---- fused pool+head: block per graph; wave 0 finishes post/ro/log_softmax
// in-register from the pooled row. h is bf16. ----
__global__ __launch_bounds__(256) void pool_head_kernel(
    const unsigned short* __restrict__ h, const int* __restrict__ batch,
    const float* __restrict__ Wp, const float* __restrict__ bp,
    const float* __restrict__ Wr, const float* __restrict__ br,
    float* __restrict__ out)
{
    const int graph = blockIdx.x;
    int l = 0, r = N_NODES;
    while (l < r) { int m = (l + r) >> 1; if (batch[m] < graph) l = m + 1; else r = m; }
    const int lo = l;
    r = N_NODES;
    while (l < r) { int m = (l + r) >> 1; if (batch[m] < graph + 1) l = m + 1; else r = m; }
    const int hi = l;

    const int lane = threadIdx.x & 63;
    const int wave = threadIdx.x >> 6;
    float acc = 0.0f;
    for (int i = lo + wave; i < hi; i += 4)
        acc += __uint_as_float(((unsigned)h[(size_t)i * N_HID + lane]) << 16);
    __shared__ float sacc[4][N_HID];
    sacc[wave][lane] = acc;
    __syncthreads();
    if (wave != 0) return;

    const float gv = sacc[0][lane] + sacc[1][lane] + sacc[2][lane] + sacc[3][lane];
    float acc2 = bp[lane];
#pragma unroll
    for (int k = 0; k < N_HID; ++k) {
        const float gk = __int_as_float(
            __builtin_amdgcn_readlane(__float_as_int(gv), k));  // exec-ignoring
        acc2 = fmaf(gk, Wp[k * N_HID + lane], acc2);
    }
    const float y = fmaxf(acc2, 0.f);

    float logit = (lane < N_CLASS) ? br[lane] : 0.f;
#pragma unroll
    for (int k = 0; k < N_HID; ++k) {
        const float yk = __int_as_float(
            __builtin_amdgcn_readlane(__float_as_int(y), k));
        if (lane < N_CLASS)
            logit = fmaf(yk, Wr[k * N_CLASS + lane], logit);
    }

    __shared__ float slog[N_CLASS];
    if (lane < N_CLASS) slog[lane] = logit;
    if (lane < N_CLASS) {
        float m = -INFINITY;
#pragma unroll
        for (int c = 0; c < N_CLASS; ++c) m = fmaxf(m, slog[c]);
        float sum = 0.0f;
#pragma unroll
        for (int c = 0; c < N_CLASS; ++c) sum += expf(slog[c] - m);
        out[(size_t)graph * N_CLASS + lane] = logit - m - logf(sum);
    }
}

extern "C" void kernel_launch(void* const* d_in, const int* in_sizes, int n_in,
                              void* d_out, int out_size, void* d_ws, size_t ws_size,
                              hipStream_t stream)
{
    const float* x       = (const float*)d_in[0];
    const int*   ei      = (const int*)d_in[1];   // [2, E]: row0=src, row1=dst
    const int*   batch   = (const int*)d_in[2];
    const float* pre_w   = (const float*)d_in[3];
    const float* pre_b   = (const float*)d_in[4];
    const float* conv_w1 = (const float*)d_in[5];
    const float* conv_b1 = (const float*)d_in[6];
    const float* conv_w2 = (const float*)d_in[7];
    const float* conv_b2 = (const float*)d_in[8];
    const float* post_w  = (const float*)d_in[9];
    const float* post_b  = (const float*)d_in[10];
    const float* ro_w    = (const float*)d_in[11];
    const float* ro_b    = (const float*)d_in[12];
    float* out = (float*)d_out;

    // workspace layout (~51.6 MB)
    uint2* h0   = (uint2*)d_ws;                       // 12.8 MB (bf16 h)
    uint2* h1   = h0 + (size_t)N_NODES * 16;          // 12.8 MB
    int*   deg  = (int*)(h1 + (size_t)N_NODES * 16);  // 400 KB
    int*   csr  = deg + N_NODES;                      // 25.6 MB fixed-stride

    hipMemsetAsync(deg, 0, N_NODES * sizeof(int), stream);

    pre_kernel<<<NTILES, 256, 0, stream>>>(x, pre_w, pre_b, h0);
    hist_fill_kernel<<<1024, 256, 0, stream>>>(ei, deg, csr);

    // 3 fused GIN layers, h ping-pong h0 -> h1 -> h0 -> h1
    gather_mlp_kernel<<<NT2, 512, 0, stream>>>(
        h0, h1, csr, deg,
        conv_w1, conv_b1, conv_w2, conv_b2);
    gather_mlp_kernel<<<NT2, 512, 0, stream>>>(
        h1, h0, csr, deg,
        conv_w1 + N_HID * N_HID, conv_b1 + N_HID,
        conv_w2 + N_HID * N_HID, conv_b2 + N_HID);
    gather_mlp_kernel<<<NT2, 512, 0, stream>>>(
        h0, h1, csr, deg,
        conv_w1 + 2 * N_HID * N_HID, conv_b1 + 2 * N_HID,
        conv_w2 + 2 * N_HID * N_HID, conv_b2 + 2 * N_HID);

    pool_head_kernel<<<N_GRAPHS, 256, 0, stream>>>(
        (const unsigned short*)h1, batch, post_w, post_b, ro_w, ro_b, out);
}

// Round 10
// 443.221 us; speedup vs baseline: 1.2179x; 1.1996x over previous
//
#include <hip/hip_runtime.h>
#include <math.h>

#define N_NODES  100000
#define N_FEAT   128
#define N_HID    64
#define N_CLASS  10
#define N_GRAPHS 1000
#define N_EDGES  1600000
#define NTILES   1563      // ceil(100000/64)   (pre kernel, 64-node tiles)
#define BLK_N    128       // gather_mlp tile
#define NT2      782       // ceil(100000/128)
#define HF_PASS  8
#define HF_RANGE 12500     // 100000/8; csr window 3.2 MB < 4 MB/XCD L2
#define CSR_STRIDE 64      // fixed bucket per node; P(deg>=64)~1e-20 @ Poisson(16)
#define EMAX_LDS 32        // staged slots per node; P(deg>32)~1e-4 -> global tail

// ---- bf16 helpers: h stored bf16 (row = 128 B); all arithmetic fp32.
__device__ __forceinline__ float bflo(unsigned u) { return __uint_as_float(u << 16); }
__device__ __forceinline__ float bfhi(unsigned u) { return __uint_as_float(u & 0xffff0000u); }
__device__ __forceinline__ unsigned bf_rne(float f) {
    unsigned u = __float_as_uint(f);
    return (u + 0x7fffu + ((u >> 16) & 1u)) >> 16;
}
__device__ __forceinline__ unsigned pack2(float a, float b) {
    return bf_rne(a) | (bf_rne(b) << 16);
}

// ---- pre: h0 = x @ pre_w + pre_b (bf16 out). 64-node tile, K in two halves,
// 34.8 KB LDS, 4 blocks/CU.
__global__ __launch_bounds__(256, 4) void pre_kernel(
    const float* __restrict__ x, const float* __restrict__ W,
    const float* __restrict__ b, uint2* __restrict__ h)
{
    __shared__ float xs[64][68];
    __shared__ float ws[64][68];
    const int tid = threadIdx.x;
    const int tx = tid & 15, ty = tid >> 4;
    const int n0 = blockIdx.x * 64;

    float acc[4][4];
#pragma unroll
    for (int i = 0; i < 4; ++i)
#pragma unroll
        for (int j = 0; j < 4; ++j) acc[i][j] = 0.f;

    for (int p = 0; p < 2; ++p) {
        __syncthreads();
#pragma unroll
        for (int t = 0; t < 4; ++t) {
            const int idx = t * 256 + tid;
            const int m = idx >> 4, kv = idx & 15;
            float4 v = make_float4(0.f, 0.f, 0.f, 0.f);
            if (n0 + m < N_NODES)
                v = *(const float4*)(x + (size_t)(n0 + m) * N_FEAT + p * 64 + kv * 4);
            *(float4*)&xs[m][kv * 4] = v;
            *(float4*)&ws[m][kv * 4] =
                *(const float4*)(W + (size_t)(p * 64 + m) * N_HID + kv * 4);
        }
        __syncthreads();
#pragma unroll 2
        for (int k4 = 0; k4 < 16; ++k4) {
            float4 a[4], bb[4];
#pragma unroll
            for (int i = 0; i < 4; ++i)
                a[i] = *(const float4*)&xs[ty + 16 * i][k4 * 4];
#pragma unroll
            for (int j = 0; j < 4; ++j)
                bb[j] = *(const float4*)&ws[k4 * 4 + j][tx * 4];
#pragma unroll
            for (int i = 0; i < 4; ++i) {
                const float* ap = (const float*)&a[i];
#pragma unroll
                for (int j = 0; j < 4; ++j) {
                    const float* bp = (const float*)&bb[j];
#pragma unroll
                    for (int c = 0; c < 4; ++c)
                        acc[i][c] = fmaf(ap[j], bp[c], acc[i][c]);
                }
            }
        }
    }

    const float4 bias = *(const float4*)(b + tx * 4);
#pragma unroll
    for (int i = 0; i < 4; ++i) {
        const int node = n0 + ty + 16 * i;
        if (node < N_NODES) {
            h[(size_t)node * 16 + tx] = make_uint2(
                pack2(acc[i][0] + bias.x, acc[i][1] + bias.y),
                pack2(acc[i][2] + bias.z, acc[i][3] + bias.w));
        }
    }
}

// ---- hist+fill: fixed-stride CSR, no scan. 8 dst-range passes keep the
// active csr window (3.2 MB) + deg window L2-resident.
__global__ __launch_bounds__(256) void hist_fill_kernel(
    const int* __restrict__ ei, int* __restrict__ deg, int* __restrict__ csr)
{
    const int stride = gridDim.x * blockDim.x;
    const int tid0 = blockIdx.x * blockDim.x + threadIdx.x;
    const int4* dst4 = (const int4*)(ei + N_EDGES);
    for (int pass = 0; pass < HF_PASS; ++pass) {
        const int lo = pass * HF_RANGE;
        const int hi = lo + HF_RANGE;
        for (int q = tid0; q < N_EDGES / 4; q += stride) {
            const int4 d = dst4[q];
            const int e0 = q * 4;
            if (d.x >= lo && d.x < hi) {
                int p = atomicAdd(&deg[d.x], 1);
                if (p < CSR_STRIDE) csr[d.x * CSR_STRIDE + p] = ei[e0];
            }
            if (d.y >= lo && d.y < hi) {
                int p = atomicAdd(&deg[d.y], 1);
                if (p < CSR_STRIDE) csr[d.y * CSR_STRIDE + p] = ei[e0 + 1];
            }
            if (d.z >= lo && d.z < hi) {
                int p = atomicAdd(&deg[d.z], 1);
                if (p < CSR_STRIDE) csr[d.z * CSR_STRIDE + p] = ei[e0 + 2];
            }
            if (d.w >= lo && d.w < hi) {
                int p = atomicAdd(&deg[d.w], 1);
                if (p < CSR_STRIDE) csr[d.w * CSR_STRIDE + p] = ei[e0 + 3];
            }
        }
    }
}

// ---- fused GIN layer v3: chain-broken gather + fp32 2-GEMM MLP.
// Gather restructure (rounds 7-9 all ~100us invariant to BW/occupancy ->
// latency-chain bound): edge indices staged to LDS up-front (coalesced),
// deg staged to LDS, one 16-lane group per node (32 independent chains per
// block), NO __shfl in the gather. Per-edge chain is just ds_read -> row
// load -> acc; iterations independent -> pipelinable.
// eidx for node r aliases as[r][36..67] (dead until that node's result
// write, which the same group does after its reads).
__global__ __launch_bounds__(512, 6) void gather_mlp_kernel(
    const uint2* __restrict__ hin, uint2* __restrict__ hout,
    const int* __restrict__ csr, const int* __restrict__ deg,
    const float* __restrict__ W1, const float* __restrict__ b1,
    const float* __restrict__ W2, const float* __restrict__ b2)
{
    __shared__ float as[BLK_N][68];   // [r][36..67] = staged eidx, then agg/z tile
    __shared__ float ws[64][68];      // W1, then W2
    __shared__ int   sdeg[BLK_N];
    const int tid = threadIdx.x;
    const int tx = tid & 15, ty = tid >> 4;   // ty = group id 0..31
    const int sub = tx;
    const int n0 = blockIdx.x * BLK_N;

    // stage W1 (latency hidden behind gather)
#pragma unroll
    for (int t = 0; t < 2; ++t) {
        const int idx = t * 512 + tid;
        const int m = idx >> 4, kv = idx & 15;
        *(float4*)&ws[m][kv * 4] = *(const float4*)(W1 + (size_t)m * N_HID + kv * 4);
    }
    // stage deg
    if (tid < BLK_N) {
        const int node = n0 + tid;
        sdeg[tid] = (node < N_NODES) ? deg[node] : 0;
    }
    // stage edge indices: first 32 slots per node -> as[r][36..67]
    // 128 nodes * 8 int4 = 1024 int4, 2 per thread, coalesced per node row
#pragma unroll
    for (int t = 0; t < 2; ++t) {
        const int idx = t * 512 + tid;        // 0..1023
        const int r = idx >> 3, s4 = idx & 7;
        const int node = n0 + r;
        int4 v = make_int4(0, 0, 0, 0);
        if (node < N_NODES)
            v = *(const int4*)(csr + (size_t)node * CSR_STRIDE + s4 * 4);
        *(int4*)((int*)&as[r][36] + s4 * 4) = v;
    }
    __syncthreads();

    // gather: group ty handles rows ty, ty+32, ty+64, ty+96
    for (int rep = 0; rep < 4; ++rep) {
        const int r = ty + 32 * rep;
        const int node = n0 + r;
        float ax = 0.f, ay = 0.f, az = 0.f, aw = 0.f;
        float bx = 0.f, by = 0.f, bz = 0.f, bw = 0.f;
        if (node < N_NODES) {
            int n = sdeg[r];
            n = n > CSR_STRIDE ? CSR_STRIDE : n;
            const uint2 a0 = hin[(size_t)node * 16 + sub];   // self term
            ax = bflo(a0.x); ay = bfhi(a0.x);
            az = bflo(a0.y); aw = bfhi(a0.y);
            const int nn = n > EMAX_LDS ? EMAX_LDS : n;
            const int* eptr = (const int*)&as[r][36];
            int e = 0;
            for (; e + 2 <= nn; e += 2) {        // 2 acc sets, indep row loads
                const int s0 = eptr[e];          // LDS broadcast read
                const int s1 = eptr[e + 1];
                const uint2 a = hin[(size_t)s0 * 16 + sub];
                const uint2 b2v = hin[(size_t)s1 * 16 + sub];
                ax += bflo(a.x);  ay += bfhi(a.x);
                az += bflo(a.y);  aw += bfhi(a.y);
                bx += bflo(b2v.x); by += bfhi(b2v.x);
                bz += bflo(b2v.y); bw += bfhi(b2v.y);
            }
            if (e < nn) {
                const int s0 = eptr[e];
                const uint2 a = hin[(size_t)s0 * 16 + sub];
                ax += bflo(a.x); ay += bfhi(a.x);
                az += bflo(a.y); aw += bfhi(a.y);
            }
            for (int t = EMAX_LDS; t < n; ++t) { // rare tail (P~1e-4)
                const int s0 = csr[(size_t)node * CSR_STRIDE + t];
                const uint2 a = hin[(size_t)s0 * 16 + sub];
                ax += bflo(a.x); ay += bfhi(a.x);
                az += bflo(a.y); aw += bfhi(a.y);
            }
        }
        // write result row (overlaps this row's eidx region — reads done)
        *(float4*)&as[r][sub * 4] =
            make_float4(ax + bx, ay + by, az + bz, aw + bw);
    }
    __syncthreads();

    // phase 1: z = relu(agg @ W1 + b1); rows ty + 32*i
    float acc[4][4];
#pragma unroll
    for (int i = 0; i < 4; ++i)
#pragma unroll
        for (int j = 0; j < 4; ++j) acc[i][j] = 0.f;
#pragma unroll 2
    for (int k4 = 0; k4 < 16; ++k4) {
        float4 a[4], bb[4];
#pragma unroll
        for (int i = 0; i < 4; ++i)
            a[i] = *(const float4*)&as[ty + 32 * i][k4 * 4];
#pragma unroll
        for (int j = 0; j < 4; ++j)
            bb[j] = *(const float4*)&ws[k4 * 4 + j][tx * 4];
#pragma unroll
        for (int i = 0; i < 4; ++i) {
            const float* ap = (const float*)&a[i];
#pragma unroll
            for (int j = 0; j < 4; ++j) {
                const float* bp = (const float*)&bb[j];
#pragma unroll
                for (int c = 0; c < 4; ++c)
                    acc[i][c] = fmaf(ap[j], bp[c], acc[i][c]);
            }
        }
    }
    const float4 bias1 = *(const float4*)(b1 + tx * 4);
    float4 z[4];
#pragma unroll
    for (int i = 0; i < 4; ++i) {
        z[i].x = fmaxf(acc[i][0] + bias1.x, 0.f);
        z[i].y = fmaxf(acc[i][1] + bias1.y, 0.f);
        z[i].z = fmaxf(acc[i][2] + bias1.z, 0.f);
        z[i].w = fmaxf(acc[i][3] + bias1.w, 0.f);
    }
    __syncthreads();               // all phase-1 reads of as/ws done
#pragma unroll
    for (int i = 0; i < 4; ++i)
        *(float4*)&as[ty + 32 * i][tx * 4] = z[i];
#pragma unroll
    for (int t = 0; t < 2; ++t) {
        const int idx = t * 512 + tid;
        const int m = idx >> 4, kv = idx & 15;
        *(float4*)&ws[m][kv * 4] = *(const float4*)(W2 + (size_t)m * N_HID + kv * 4);
    }
    __syncthreads();

    // phase 2: h = relu(z @ W2 + b2), bf16 out
#pragma unroll
    for (int i = 0; i < 4; ++i)
#pragma unroll
        for (int j = 0; j < 4; ++j) acc[i][j] = 0.f;
#pragma unroll 2
    for (int k4 = 0; k4 < 16; ++k4) {
        float4 a[4], bb[4];
#pragma unroll
        for (int i = 0; i < 4; ++i)
            a[i] = *(const float4*)&as[ty + 32 * i][k4 * 4];
#pragma unroll
        for (int j = 0; j < 4; ++j)
            bb[j] = *(const float4*)&ws[k4 * 4 + j][tx * 4];
#pragma unroll
        for (int i = 0; i < 4; ++i) {
            const float* ap = (const float*)&a[i];
#pragma unroll
            for (int j = 0; j < 4; ++j) {
                const float* bp = (const float*)&bb[j];
#pragma unroll
                for (int c = 0; c < 4; ++c)
                    acc[i][c] = fmaf(ap[j], bp[c], acc[i][c]);
            }
        }
    }
    const float4 bias2 = *(const float4*)(b2 + tx * 4);
#pragma unroll
    for (int i = 0; i < 4; ++i) {
        const int node = n0 + ty + 32 * i;
        if (node < N_NODES) {
            hout[(size_t)node * 16 + tx] = make_uint2(
                pack2(fmaxf(acc[i][0] + bias2.x, 0.f),
                      fmaxf(acc[i][1] + bias2.y, 0.f)),
                pack2(fmaxf(acc[i][2] + bias2.z, 0.f),
                      fmaxf(acc[i][3] + bias2.w, 0.f)));
        }
    }
}

// ---- fused pool+head: block per graph; wave 0 finishes post/ro/log_softmax
// in-register from the pooled row. h is bf16. ----
__global__ __launch_bounds__(256) void pool_head_kernel(
    const unsigned short* __restrict__ h, const int* __restrict__ batch,
    const float* __restrict__ Wp, const float* __restrict__ bp,
    const float* __restrict__ Wr, const float* __restrict__ br,
    float* __restrict__ out)
{
    const int graph = blockIdx.x;
    int l = 0, r = N_NODES;
    while (l < r) { int m = (l + r) >> 1; if (batch[m] < graph) l = m + 1; else r = m; }
    const int lo = l;
    r = N_NODES;
    while (l < r) { int m = (l + r) >> 1; if (batch[m] < graph + 1) l = m + 1; else r = m; }
    const int hi = l;

    const int lane = threadIdx.x & 63;
    const int wave = threadIdx.x >> 6;
    float acc = 0.0f;
    for (int i = lo + wave; i < hi; i += 4)
        acc += __uint_as_float(((unsigned)h[(size_t)i * N_HID + lane]) << 16);
    __shared__ float sacc[4][N_HID];
    sacc[wave][lane] = acc;
    __syncthreads();
    if (wave != 0) return;

    const float gv = sacc[0][lane] + sacc[1][lane] + sacc[2][lane] + sacc[3][lane];
    float acc2 = bp[lane];
#pragma unroll
    for (int k = 0; k < N_HID; ++k) {
        const float gk = __int_as_float(
            __builtin_amdgcn_readlane(__float_as_int(gv), k));  // exec-ignoring
        acc2 = fmaf(gk, Wp[k * N_HID + lane], acc2);
    }
    const float y = fmaxf(acc2, 0.f);

    float logit = (lane < N_CLASS) ? br[lane] : 0.f;
#pragma unroll
    for (int k = 0; k < N_HID; ++k) {
        const float yk = __int_as_float(
            __builtin_amdgcn_readlane(__float_as_int(y), k));
        if (lane < N_CLASS)
            logit = fmaf(yk, Wr[k * N_CLASS + lane], logit);
    }

    __shared__ float slog[N_CLASS];
    if (lane < N_CLASS) slog[lane] = logit;
    if (lane < N_CLASS) {
        float m = -INFINITY;
#pragma unroll
        for (int c = 0; c < N_CLASS; ++c) m = fmaxf(m, slog[c]);
        float sum = 0.0f;
#pragma unroll
        for (int c = 0; c < N_CLASS; ++c) sum += expf(slog[c] - m);
        out[(size_t)graph * N_CLASS + lane] = logit - m - logf(sum);
    }
}

extern "C" void kernel_launch(void* const* d_in, const int* in_sizes, int n_in,
                              void* d_out, int out_size, void* d_ws, size_t ws_size,
                              hipStream_t stream)
{
    const float* x       = (const float*)d_in[0];
    const int*   ei      = (const int*)d_in[1];   // [2, E]: row0=src, row1=dst
    const int*   batch   = (const int*)d_in[2];
    const float* pre_w   = (const float*)d_in[3];
    const float* pre_b   = (const float*)d_in[4];
    const float* conv_w1 = (const float*)d_in[5];
    const float* conv_b1 = (const float*)d_in[6];
    const float* conv_w2 = (const float*)d_in[7];
    const float* conv_b2 = (const float*)d_in[8];
    const float* post_w  = (const float*)d_in[9];
    const float* post_b  = (const float*)d_in[10];
    const float* ro_w    = (const float*)d_in[11];
    const float* ro_b    = (const float*)d_in[12];
    float* out = (float*)d_out;

    // workspace layout (~51.6 MB)
    uint2* h0   = (uint2*)d_ws;                       // 12.8 MB (bf16 h)
    uint2* h1   = h0 + (size_t)N_NODES * 16;          // 12.8 MB
    int*   deg  = (int*)(h1 + (size_t)N_NODES * 16);  // 400 KB
    int*   csr  = deg + N_NODES;                      // 25.6 MB fixed-stride

    hipMemsetAsync(deg, 0, N_NODES * sizeof(int), stream);

    pre_kernel<<<NTILES, 256, 0, stream>>>(x, pre_w, pre_b, h0);
    hist_fill_kernel<<<1024, 256, 0, stream>>>(ei, deg, csr);

    // 3 fused GIN layers, h ping-pong h0 -> h1 -> h0 -> h1
    gather_mlp_kernel<<<NT2, 512, 0, stream>>>(
        h0, h1, csr, deg,
        conv_w1, conv_b1, conv_w2, conv_b2);
    gather_mlp_kernel<<<NT2, 512, 0, stream>>>(
        h1, h0, csr, deg,
        conv_w1 + N_HID * N_HID, conv_b1 + N_HID,
        conv_w2 + N_HID * N_HID, conv_b2 + N_HID);
    gather_mlp_kernel<<<NT2, 512, 0, stream>>>(
        h0, h1, csr, deg,
        conv_w1 + 2 * N_HID * N_HID, conv_b1 + 2 * N_HID,
        conv_w2 + 2 * N_HID * N_HID, conv_b2 + 2 * N_HID);

    pool_head_kernel<<<N_GRAPHS, 256, 0, stream>>>(
        (const unsigned short*)h1, batch, post_w, post_b, ro_w, ro_b, out);
}

// Round 11
// 411.343 us; speedup vs baseline: 1.3123x; 1.0775x over previous
//
#include <hip/hip_runtime.h>
#include <math.h>

#define N_NODES  100000
#define N_FEAT   128
#define N_HID    64
#define N_CLASS  10
#define N_GRAPHS 1000
#define N_EDGES  1600000
#define NTILES   1563      // ceil(100000/64)   (pre kernel, 64-node tiles)
#define BLK_N    128       // gather_mlp tile
#define NT2      782       // ceil(100000/128)
#define HF_PASS  8
#define HF_RANGE 12500     // 100000/8; csr window 3.2 MB < 4 MB/XCD L2
#define CSR_STRIDE 64      // fixed bucket per node; P(deg>=64)~1e-20 @ Poisson(16)
#define EMAX_LDS 32        // staged slots per node; P(deg>32)~1e-4 -> global tail

// ---- bf16 helpers: h stored bf16 (row = 128 B); all arithmetic fp32.
__device__ __forceinline__ float bflo(unsigned u) { return __uint_as_float(u << 16); }
__device__ __forceinline__ float bfhi(unsigned u) { return __uint_as_float(u & 0xffff0000u); }
__device__ __forceinline__ unsigned bf_rne(float f) {
    unsigned u = __float_as_uint(f);
    return (u + 0x7fffu + ((u >> 16) & 1u)) >> 16;
}
__device__ __forceinline__ unsigned pack2(float a, float b) {
    return bf_rne(a) | (bf_rne(b) << 16);
}

// ---- pre: h0 = x @ pre_w + pre_b (bf16 out). 64-node tile, K in two halves,
// 34.8 KB LDS, 4 blocks/CU.
__global__ __launch_bounds__(256, 4) void pre_kernel(
    const float* __restrict__ x, const float* __restrict__ W,
    const float* __restrict__ b, uint2* __restrict__ h)
{
    __shared__ float xs[64][68];
    __shared__ float ws[64][68];
    const int tid = threadIdx.x;
    const int tx = tid & 15, ty = tid >> 4;
    const int n0 = blockIdx.x * 64;

    float acc[4][4];
#pragma unroll
    for (int i = 0; i < 4; ++i)
#pragma unroll
        for (int j = 0; j < 4; ++j) acc[i][j] = 0.f;

    for (int p = 0; p < 2; ++p) {
        __syncthreads();
#pragma unroll
        for (int t = 0; t < 4; ++t) {
            const int idx = t * 256 + tid;
            const int m = idx >> 4, kv = idx & 15;
            float4 v = make_float4(0.f, 0.f, 0.f, 0.f);
            if (n0 + m < N_NODES)
                v = *(const float4*)(x + (size_t)(n0 + m) * N_FEAT + p * 64 + kv * 4);
            *(float4*)&xs[m][kv * 4] = v;
            *(float4*)&ws[m][kv * 4] =
                *(const float4*)(W + (size_t)(p * 64 + m) * N_HID + kv * 4);
        }
        __syncthreads();
#pragma unroll 2
        for (int k4 = 0; k4 < 16; ++k4) {
            float4 a[4], bb[4];
#pragma unroll
            for (int i = 0; i < 4; ++i)
                a[i] = *(const float4*)&xs[ty + 16 * i][k4 * 4];
#pragma unroll
            for (int j = 0; j < 4; ++j)
                bb[j] = *(const float4*)&ws[k4 * 4 + j][tx * 4];
#pragma unroll
            for (int i = 0; i < 4; ++i) {
                const float* ap = (const float*)&a[i];
#pragma unroll
                for (int j = 0; j < 4; ++j) {
                    const float* bp = (const float*)&bb[j];
#pragma unroll
                    for (int c = 0; c < 4; ++c)
                        acc[i][c] = fmaf(ap[j], bp[c], acc[i][c]);
                }
            }
        }
    }

    const float4 bias = *(const float4*)(b + tx * 4);
#pragma unroll
    for (int i = 0; i < 4; ++i) {
        const int node = n0 + ty + 16 * i;
        if (node < N_NODES) {
            h[(size_t)node * 16 + tx] = make_uint2(
                pack2(acc[i][0] + bias.x, acc[i][1] + bias.y),
                pack2(acc[i][2] + bias.z, acc[i][3] + bias.w));
        }
    }
}

// ---- hist+fill: fixed-stride CSR, no scan. 8 dst-range passes keep the
// active csr window (3.2 MB) + deg window L2-resident.
__global__ __launch_bounds__(256) void hist_fill_kernel(
    const int* __restrict__ ei, int* __restrict__ deg, int* __restrict__ csr)
{
    const int stride = gridDim.x * blockDim.x;
    const int tid0 = blockIdx.x * blockDim.x + threadIdx.x;
    const int4* dst4 = (const int4*)(ei + N_EDGES);
    for (int pass = 0; pass < HF_PASS; ++pass) {
        const int lo = pass * HF_RANGE;
        const int hi = lo + HF_RANGE;
        for (int q = tid0; q < N_EDGES / 4; q += stride) {
            const int4 d = dst4[q];
            const int e0 = q * 4;
            if (d.x >= lo && d.x < hi) {
                int p = atomicAdd(&deg[d.x], 1);
                if (p < CSR_STRIDE) csr[d.x * CSR_STRIDE + p] = ei[e0];
            }
            if (d.y >= lo && d.y < hi) {
                int p = atomicAdd(&deg[d.y], 1);
                if (p < CSR_STRIDE) csr[d.y * CSR_STRIDE + p] = ei[e0 + 1];
            }
            if (d.z >= lo && d.z < hi) {
                int p = atomicAdd(&deg[d.z], 1);
                if (p < CSR_STRIDE) csr[d.z * CSR_STRIDE + p] = ei[e0 + 2];
            }
            if (d.w >= lo && d.w < hi) {
                int p = atomicAdd(&deg[d.w], 1);
                if (p < CSR_STRIDE) csr[d.w * CSR_STRIDE + p] = ei[e0 + 3];
            }
        }
    }
}

// ---- fused GIN layer v4: 8-deep pipelined gather + fp32 2-GEMM MLP.
// v3 (round 10) broke the shfl chain -> 103->~80us; its e-loop still held
// only 2 loads in flight per group. v4 batches 8 row-loads per iteration
// (clamped index + predicated accumulate: csr slots >= deg hold poison, so
// padding re-loads slot nn-1 which is L1-hot) -> 4x memory concurrency.
__global__ __launch_bounds__(512, 6) void gather_mlp_kernel(
    const uint2* __restrict__ hin, uint2* __restrict__ hout,
    const int* __restrict__ csr, const int* __restrict__ deg,
    const float* __restrict__ W1, const float* __restrict__ b1,
    const float* __restrict__ W2, const float* __restrict__ b2)
{
    __shared__ float as[BLK_N][68];   // [r][36..67] = staged eidx, then agg/z tile
    __shared__ float ws[64][68];      // W1, then W2
    __shared__ int   sdeg[BLK_N];
    const int tid = threadIdx.x;
    const int tx = tid & 15, ty = tid >> 4;   // ty = group id 0..31
    const int sub = tx;
    const int n0 = blockIdx.x * BLK_N;

    // stage W1 (latency hidden behind gather)
#pragma unroll
    for (int t = 0; t < 2; ++t) {
        const int idx = t * 512 + tid;
        const int m = idx >> 4, kv = idx & 15;
        *(float4*)&ws[m][kv * 4] = *(const float4*)(W1 + (size_t)m * N_HID + kv * 4);
    }
    // stage deg
    if (tid < BLK_N) {
        const int node = n0 + tid;
        sdeg[tid] = (node < N_NODES) ? deg[node] : 0;
    }
    // stage edge indices: first 32 slots per node -> as[r][36..67]
#pragma unroll
    for (int t = 0; t < 2; ++t) {
        const int idx = t * 512 + tid;        // 0..1023
        const int r = idx >> 3, s4 = idx & 7;
        const int node = n0 + r;
        int4 v = make_int4(0, 0, 0, 0);
        if (node < N_NODES)
            v = *(const int4*)(csr + (size_t)node * CSR_STRIDE + s4 * 4);
        *(int4*)((int*)&as[r][36] + s4 * 4) = v;
    }
    __syncthreads();

    // gather: group ty handles rows ty, ty+32, ty+64, ty+96
    for (int rep = 0; rep < 4; ++rep) {
        const int r = ty + 32 * rep;
        const int node = n0 + r;
        float ax = 0.f, ay = 0.f, az = 0.f, aw = 0.f;
        float bx = 0.f, by = 0.f, bz = 0.f, bw = 0.f;
        if (node < N_NODES) {
            int n = sdeg[r];
            n = n > CSR_STRIDE ? CSR_STRIDE : n;
            const uint2 a0 = hin[(size_t)node * 16 + sub];   // self term
            ax = bflo(a0.x); ay = bfhi(a0.x);
            az = bflo(a0.y); aw = bfhi(a0.y);
            const int nn = n > EMAX_LDS ? EMAX_LDS : n;
            const int* eptr = (const int*)&as[r][36];
            if (nn > 0) {
                for (int eb = 0; eb < nn; eb += 8) {   // 8 loads in flight
                    uint2 rv[8];
#pragma unroll
                    for (int u = 0; u < 8; ++u) {
                        const int idx = eb + u;
                        const int cl = idx < nn ? idx : nn - 1;  // clamp: slots>=deg are poison
                        rv[u] = hin[(size_t)eptr[cl] * 16 + sub];
                    }
#pragma unroll
                    for (int u = 0; u < 8; u += 2) {
                        if (eb + u < nn) {
                            ax += bflo(rv[u].x); ay += bfhi(rv[u].x);
                            az += bflo(rv[u].y); aw += bfhi(rv[u].y);
                        }
                        if (eb + u + 1 < nn) {
                            bx += bflo(rv[u + 1].x); by += bfhi(rv[u + 1].x);
                            bz += bflo(rv[u + 1].y); bw += bfhi(rv[u + 1].y);
                        }
                    }
                }
            }
            for (int t = EMAX_LDS; t < n; ++t) { // rare tail (P~1e-4)
                const int s0 = csr[(size_t)node * CSR_STRIDE + t];
                const uint2 a = hin[(size_t)s0 * 16 + sub];
                ax += bflo(a.x); ay += bfhi(a.x);
                az += bflo(a.y); aw += bfhi(a.y);
            }
        }
        // write result row (overlaps this row's eidx region — reads done)
        *(float4*)&as[r][sub * 4] =
            make_float4(ax + bx, ay + by, az + bz, aw + bw);
    }
    __syncthreads();

    // phase 1: z = relu(agg @ W1 + b1); rows ty + 32*i
    float acc[4][4];
#pragma unroll
    for (int i = 0; i < 4; ++i)
#pragma unroll
        for (int j = 0; j < 4; ++j) acc[i][j] = 0.f;
#pragma unroll 2
    for (int k4 = 0; k4 < 16; ++k4) {
        float4 a[4], bb[4];
#pragma unroll
        for (int i = 0; i < 4; ++i)
            a[i] = *(const float4*)&as[ty + 32 * i][k4 * 4];
#pragma unroll
        for (int j = 0; j < 4; ++j)
            bb[j] = *(const float4*)&ws[k4 * 4 + j][tx * 4];
#pragma unroll
        for (int i = 0; i < 4; ++i) {
            const float* ap = (const float*)&a[i];
#pragma unroll
            for (int j = 0; j < 4; ++j) {
                const float* bp = (const float*)&bb[j];
#pragma unroll
                for (int c = 0; c < 4; ++c)
                    acc[i][c] = fmaf(ap[j], bp[c], acc[i][c]);
            }
        }
    }
    const float4 bias1 = *(const float4*)(b1 + tx * 4);
    float4 z[4];
#pragma unroll
    for (int i = 0; i < 4; ++i) {
        z[i].x = fmaxf(acc[i][0] + bias1.x, 0.f);
        z[i].y = fmaxf(acc[i][1] + bias1.y, 0.f);
        z[i].z = fmaxf(acc[i][2] + bias1.z, 0.f);
        z[i].w = fmaxf(acc[i][3] + bias1.w, 0.f);
    }
    __syncthreads();               // all phase-1 reads of as/ws done
#pragma unroll
    for (int i = 0; i < 4; ++i)
        *(float4*)&as[ty + 32 * i][tx * 4] = z[i];
#pragma unroll
    for (int t = 0; t < 2; ++t) {
        const int idx = t * 512 + tid;
        const int m = idx >> 4, kv = idx & 15;
        *(float4*)&ws[m][kv * 4] = *(const float4*)(W2 + (size_t)m * N_HID + kv * 4);
    }
    __syncthreads();

    // phase 2: h = relu(z @ W2 + b2), bf16 out
#pragma unroll
    for (int i = 0; i < 4; ++i)
#pragma unroll
        for (int j = 0; j < 4; ++j) acc[i][j] = 0.f;
#pragma unroll 2
    for (int k4 = 0; k4 < 16; ++k4) {
        float4 a[4], bb[4];
#pragma unroll
        for (int i = 0; i < 4; ++i)
            a[i] = *(const float4*)&as[ty + 32 * i][k4 * 4];
#pragma unroll
        for (int j = 0; j < 4; ++j)
            bb[j] = *(const float4*)&ws[k4 * 4 + j][tx * 4];
#pragma unroll
        for (int i = 0; i < 4; ++i) {
            const float* ap = (const float*)&a[i];
#pragma unroll
            for (int j = 0; j < 4; ++j) {
                const float* bp = (const float*)&bb[j];
#pragma unroll
                for (int c = 0; c < 4; ++c)
                    acc[i][c] = fmaf(ap[j], bp[c], acc[i][c]);
            }
        }
    }
    const float4 bias2 = *(const float4*)(b2 + tx * 4);
#pragma unroll
    for (int i = 0; i < 4; ++i) {
        const int node = n0 + ty + 32 * i;
        if (node < N_NODES) {
            hout[(size_t)node * 16 + tx] = make_uint2(
                pack2(fmaxf(acc[i][0] + bias2.x, 0.f),
                      fmaxf(acc[i][1] + bias2.y, 0.f)),
                pack2(fmaxf(acc[i][2] + bias2.z, 0.f),
                      fmaxf(acc[i][3] + bias2.w, 0.f)));
        }
    }
}

// ---- fused pool+head: block per graph; wave 0 finishes post/ro/log_softmax
// in-register from the pooled row. h is bf16. ----
__global__ __launch_bounds__(256) void pool_head_kernel(
    const unsigned short* __restrict__ h, const int* __restrict__ batch,
    const float* __restrict__ Wp, const float* __restrict__ bp,
    const float* __restrict__ Wr, const float* __restrict__ br,
    float* __restrict__ out)
{
    const int graph = blockIdx.x;
    int l = 0, r = N_NODES;
    while (l < r) { int m = (l + r) >> 1; if (batch[m] < graph) l = m + 1; else r = m; }
    const int lo = l;
    r = N_NODES;
    while (l < r) { int m = (l + r) >> 1; if (batch[m] < graph + 1) l = m + 1; else r = m; }
    const int hi = l;

    const int lane = threadIdx.x & 63;
    const int wave = threadIdx.x >> 6;
    float acc = 0.0f;
    for (int i = lo + wave; i < hi; i += 4)
        acc += __uint_as_float(((unsigned)h[(size_t)i * N_HID + lane]) << 16);
    __shared__ float sacc[4][N_HID];
    sacc[wave][lane] = acc;
    __syncthreads();
    if (wave != 0) return;

    const float gv = sacc[0][lane] + sacc[1][lane] + sacc[2][lane] + sacc[3][lane];
    float acc2 = bp[lane];
#pragma unroll
    for (int k = 0; k < N_HID; ++k) {
        const float gk = __int_as_float(
            __builtin_amdgcn_readlane(__float_as_int(gv), k));  // exec-ignoring
        acc2 = fmaf(gk, Wp[k * N_HID + lane], acc2);
    }
    const float y = fmaxf(acc2, 0.f);

    float logit = (lane < N_CLASS) ? br[lane] : 0.f;
#pragma unroll
    for (int k = 0; k < N_HID; ++k) {
        const float yk = __int_as_float(
            __builtin_amdgcn_readlane(__float_as_int(y), k));
        if (lane < N_CLASS)
            logit = fmaf(yk, Wr[k * N_CLASS + lane], logit);
    }

    __shared__ float slog[N_CLASS];
    if (lane < N_CLASS) slog[lane] = logit;
    if (lane < N_CLASS) {
        float m = -INFINITY;
#pragma unroll
        for (int c = 0; c < N_CLASS; ++c) m = fmaxf(m, slog[c]);
        float sum = 0.0f;
#pragma unroll
        for (int c = 0; c < N_CLASS; ++c) sum += expf(slog[c] - m);
        out[(size_t)graph * N_CLASS + lane] = logit - m - logf(sum);
    }
}

extern "C" void kernel_launch(void* const* d_in, const int* in_sizes, int n_in,
                              void* d_out, int out_size, void* d_ws, size_t ws_size,
                              hipStream_t stream)
{
    const float* x       = (const float*)d_in[0];
    const int*   ei      = (const int*)d_in[1];   // [2, E]: row0=src, row1=dst
    const int*   batch   = (const int*)d_in[2];
    const float* pre_w   = (const float*)d_in[3];
    const float* pre_b   = (const float*)d_in[4];
    const float* conv_w1 = (const float*)d_in[5];
    const float* conv_b1 = (const float*)d_in[6];
    const float* conv_w2 = (const float*)d_in[7];
    const float* conv_b2 = (const float*)d_in[8];
    const float* post_w  = (const float*)d_in[9];
    const float* post_b  = (const float*)d_in[10];
    const float* ro_w    = (const float*)d_in[11];
    const float* ro_b    = (const float*)d_in[12];
    float* out = (float*)d_out;

    // workspace layout (~51.6 MB)
    uint2* h0   = (uint2*)d_ws;                       // 12.8 MB (bf16 h)
    uint2* h1   = h0 + (size_t)N_NODES * 16;          // 12.8 MB
    int*   deg  = (int*)(h1 + (size_t)N_NODES * 16);  // 400 KB
    int*   csr  = deg + N_NODES;                      // 25.6 MB fixed-stride

    hipMemsetAsync(deg, 0, N_NODES * sizeof(int), stream);

    pre_kernel<<<NTILES, 256, 0, stream>>>(x, pre_w, pre_b, h0);
    hist_fill_kernel<<<1024, 256, 0, stream>>>(ei, deg, csr);

    // 3 fused GIN layers, h ping-pong h0 -> h1 -> h0 -> h1
    gather_mlp_kernel<<<NT2, 512, 0, stream>>>(
        h0, h1, csr, deg,
        conv_w1, conv_b1, conv_w2, conv_b2);
    gather_mlp_kernel<<<NT2, 512, 0, stream>>>(
        h1, h0, csr, deg,
        conv_w1 + N_HID * N_HID, conv_b1 + N_HID,
        conv_w2 + N_HID * N_HID, conv_b2 + N_HID);
    gather_mlp_kernel<<<NT2, 512, 0, stream>>>(
        h0, h1, csr, deg,
        conv_w1 + 2 * N_HID * N_HID, conv_b1 + 2 * N_HID,
        conv_w2 + 2 * N_HID * N_HID, conv_b2 + 2 * N_HID);

    pool_head_kernel<<<N_GRAPHS, 256, 0, stream>>>(
        (const unsigned short*)h1, batch, post_w, post_b, ro_w, ro_b, out);
}